// Round 11
// baseline (210.081 us; speedup 1.0000x reference)
//
#include <hip/hip_runtime.h>

#define TLF_N     500000
#define TLF_ITERS 10
#define TLF_GRID  3125   // 3125 blocks * 10 iters * 4 waves * 4 data rows = 500000

typedef short bf16x8 __attribute__((ext_vector_type(8)));
typedef float f32x4  __attribute__((ext_vector_type(4)));
typedef int   i32x4  __attribute__((ext_vector_type(4)));

#define LDSFENCE asm volatile("s_waitcnt lgkmcnt(0)" ::: "memory")

__device__ __forceinline__ int cvt_pk(float lo, float hi) {
  int r;
  asm("v_cvt_pk_bf16_f32 %0, %1, %2" : "=v"(r) : "v"(lo), "v"(hi));
  return r;
}

__device__ __forceinline__ bf16x8 pack8f(float a0, float a1, float a2, float a3,
                                         float a4, float a5, float a6, float a7) {
  i32x4 r;
  r[0] = cvt_pk(a0, a1); r[1] = cvt_pk(a2, a3);
  r[2] = cvt_pk(a4, a5); r[3] = cvt_pk(a6, a7);
  return __builtin_bit_cast(bf16x8, r);
}

template<int CTRL>
__device__ __forceinline__ float dppf(float x) {
  return __builtin_bit_cast(float, __builtin_amdgcn_update_dpp(
      0, __builtin_bit_cast(int, x), CTRL, 0xF, 0xF, true));
}

// quad rotate by D: lane c receives value of lane (c&~3) | ((c+D)&3)
template<int D>
__device__ __forceinline__ float rot4(float x) {
  if constexpr (D == 0) return x;
  else if constexpr (D == 1) return dppf<0x39>(x);   // quad_perm [1,2,3,0]
  else if constexpr (D == 2) return dppf<0x4E>(x);   // quad_perm [2,3,0,1]
  else                       return dppf<0x93>(x);   // quad_perm [3,0,1,2]
}

// pair-sum over lanes {l, l^16} / {l, l^32}. PROVEN (round 6): shfl_xor.
// (permlane16/32_swap experiments, rounds 7-10, all failed: hand-asm hit
// aliasing + hazard issues; builtin's semantics deterministically differ
// from the assumed row-swap model — identical wrong absmax across variants.)
__device__ __forceinline__ float sum16(float x) {
  return x + __shfl_xor(x, 16, 64);
}
__device__ __forceinline__ float sum32(float x) {
  return x + __shfl_xor(x, 32, 64);
}

__device__ __forceinline__ f32x4 ldc4(const float* p) {
  return *reinterpret_cast<const f32x4*>(p);
}

__launch_bounds__(256, 4)
__global__ void tlf_kernel(const float* __restrict__ tokens,
                           const float* __restrict__ amask,
                           const float* __restrict__ type_emb,
                           const float* __restrict__ ipw,
                           const float* __restrict__ ipb,
                           const float* __restrict__ opw,
                           const float* __restrict__ opb,
                           const float* __restrict__ l1sv,
                           const float* __restrict__ l1bv,
                           const float* __restrict__ w1,
                           const float* __restrict__ b1v,
                           const float* __restrict__ w2,
                           const float* __restrict__ b2v,
                           const float* __restrict__ l2sv,
                           const float* __restrict__ l2bv,
                           const float* __restrict__ gwv,
                           const float* __restrict__ gbv,
                           float* __restrict__ out) {
  // wave-uniform per-g constants (f32, broadcast reads), shared by all 4 waves:
  // slots (4 floats each): 0..5 qkv bias | 6,7 bo | 8,9 b1' | 10,11 b2+l1b
  //                        | 12,13 l1s | 14,15 l2s | 16,17 l2b | 18,19 gw
  __shared__ float cLDS[4 * 80];

  const int w  = threadIdx.x >> 6;// wave 0..3
  const int l  = threadIdx.x & 63;
  const int g  = l >> 4;           // k-subgroup / channel block
  const int c  = l & 15;           // column lane: token-row within tile
  const int g4 = g << 2;

  const float isq = 0.3535533905932738f;  // 1/sqrt(HD)

  // ---- weight A-frags (rows 16t+c, k-cols P(8g+j) = {4g+j} U {16+4g+j}) ----
  bf16x8 aw[6], ao[2], a1[2], a2[2];
  #pragma unroll
  for (int t = 0; t < 6; ++t) {
    const float s = (t < 2) ? isq : 1.0f;
    const float* r0 = ipw + (16 * t + c) * 32;
    const float4 wa = *(const float4*)(r0 + g4);
    const float4 wb = *(const float4*)(r0 + 16 + g4);
    aw[t] = pack8f(wa.x * s, wa.y * s, wa.z * s, wa.w * s,
                   wb.x * s, wb.y * s, wb.z * s, wb.w * s);
  }
  const float4 ls0 = *(const float4*)(l1sv + g4);
  const float4 ls1 = *(const float4*)(l1sv + 16 + g4);
  #pragma unroll
  for (int t = 0; t < 2; ++t) {
    const float* r0 = opw + (16 * t + c) * 32;
    const float* r1 = w1  + (16 * t + c) * 32;
    const float* r2 = w2  + (16 * t + c) * 32;
    float4 wa, wb;
    wa = *(const float4*)(r0 + g4); wb = *(const float4*)(r0 + 16 + g4);
    ao[t] = pack8f(wa.x, wa.y, wa.z, wa.w, wb.x, wb.y, wb.z, wb.w);
    wa = *(const float4*)(r1 + g4); wb = *(const float4*)(r1 + 16 + g4);
    a1[t] = pack8f(wa.x * ls0.x, wa.y * ls0.y, wa.z * ls0.z, wa.w * ls0.w,
                   wb.x * ls1.x, wb.y * ls1.y, wb.z * ls1.z, wb.w * ls1.w);
    wa = *(const float4*)(r2 + g4); wb = *(const float4*)(r2 + 16 + g4);
    a2[t] = pack8f(wa.x, wa.y, wa.z, wa.w, wb.x, wb.y, wb.z, wb.w);
  }

  // ---- per-g constants -> LDS (all waves write identical values; in-wave
  //      write->read order via lgkmcnt; cross-wave writes are same-value) ----
  if (c == 0) {
    float* cp = cLDS + g * 80;
    #pragma unroll
    for (int t = 0; t < 6; ++t) {
      const float s = (t < 2) ? isq : 1.0f;
      #pragma unroll
      for (int m = 0; m < 4; ++m) cp[4 * t + m] = ipb[16 * t + g4 + m] * s;
    }
    #pragma unroll
    for (int t = 0; t < 2; ++t)
      #pragma unroll
      for (int m = 0; m < 4; ++m) {
        const int r = 16 * t + g4 + m;
        cp[24 + 4 * t + m] = opb[r];
        cp[40 + 4 * t + m] = b2v[r] + l1bv[r];
        cp[48 + 4 * t + m] = l1sv[r];
        cp[56 + 4 * t + m] = l2sv[r];
        cp[64 + 4 * t + m] = l2bv[r];
        cp[72 + 4 * t + m] = gwv[r];
      }
    // b1'[f2] = b1[f2] + sum_f l1b[f] * W1[f2][f]
    #pragma unroll
    for (int t = 0; t < 2; ++t)
      #pragma unroll
      for (int m = 0; m < 4; ++m) {
        const int r = 16 * t + g4 + m;
        float a = b1v[r];
        const float* wrow = w1 + r * 32;
        #pragma unroll
        for (int q8 = 0; q8 < 8; ++q8) {
          const float4 wv = *(const float4*)(wrow + q8 * 4);
          const float4 lb = *(const float4*)(l1bv + q8 * 4);
          a += wv.x * lb.x + wv.y * lb.y + wv.z * lb.z + wv.w * lb.w;
        }
        cp[32 + 4 * t + m] = a;
      }
  }
  LDSFENCE;

  // type_emb in B-frag layout: token m=c&3, channels P
  const float* tb = type_emb + (c & 3) * 32;
  const float4 te0 = *(const float4*)(tb + g4);
  const float4 te1 = *(const float4*)(tb + 16 + g4);
  const float gbs = gbv[0];

  // wave w handles tile = (block*ITERS + it)*4 + w
  const size_t tileW0 = ((size_t)blockIdx.x * TLF_ITERS) * 4 + w;

  // prologue prefetch
  float4 nxa, nxb; float nmsk;
  {
    const float* tp = tokens + (tileW0 * 16 + c) * 32;
    nxa = *(const float4*)(tp + g4);
    nxb = *(const float4*)(tp + 16 + g4);
    nmsk = amask[tileW0 * 16 + c];
  }

  for (int it = 0; it < TLF_ITERS; ++it) {
    const size_t tile = tileW0 + (size_t)it * 4;
    const float4 xa = nxa, xb = nxb;
    const float msk = nmsk;
    if (it + 1 < TLF_ITERS) {
      const float* tp = tokens + ((tile + 4) * 16 + c) * 32;
      nxa = *(const float4*)(tp + g4);
      nxb = *(const float4*)(tp + 16 + g4);
      nmsk = amask[(tile + 4) * 16 + c];
    }

    // LICM-defeating opaque offset for per-iter LDS const reads (32-bit, safe)
    int cgo = g * 80;
    asm volatile("" : "+v"(cgo));
    const float* cg = cLDS + cgo;

    // ---- x = tokens + te (f32, kept for exact residual) ----
    float x0[4] = {xa.x + te0.x, xa.y + te0.y, xa.z + te0.z, xa.w + te0.w};
    float x1[4] = {xb.x + te1.x, xb.y + te1.y, xb.z + te1.z, xb.w + te1.w};
    const bf16x8 bx = pack8f(x0[0], x0[1], x0[2], x0[3],
                             x1[0], x1[1], x1[2], x1[3]);

    // ---- Q, K (transposed outputs: lane(g,c) holds f=16t+4g+m, token c) ----
    f32x4 qa[2], ka[2];
    #pragma unroll
    for (int t = 0; t < 2; ++t)
      qa[t] = __builtin_amdgcn_mfma_f32_16x16x32_bf16(aw[t], bx, ldc4(cg + 4 * t), 0, 0, 0);
    #pragma unroll
    for (int t = 0; t < 2; ++t)
      ka[t] = __builtin_amdgcn_mfma_f32_16x16x32_bf16(aw[2 + t], bx, ldc4(cg + 8 + 4 * t), 0, 0, 0);

    // ---- scores + softmax (quad-DPP token rotations; shfl_xor16 joins
    //      head halves; mask bias folded into the fma seed at half weight —
    //      lanes l and l^16 share c hence msk, so the join doubles it) ----
    const float bself = (msk > 0.f) ? 0.f : -1e9f;
    float hb[4];
    hb[0] = bself * 0.5f;
    hb[1] = rot4<1>(hb[0]); hb[2] = rot4<2>(hb[0]); hb[3] = rot4<3>(hb[0]);

    float wat[2][4];
    #pragma unroll
    for (int t = 0; t < 2; ++t) {
      float att[4];
#define TLF_SCORE(d)                                                        \
      { float p = fmaf(qa[t][0], rot4<d>(ka[t][0]), hb[d]);                 \
        p = fmaf(qa[t][1], rot4<d>(ka[t][1]), p);                           \
        p = fmaf(qa[t][2], rot4<d>(ka[t][2]), p);                           \
        p = fmaf(qa[t][3], rot4<d>(ka[t][3]), p);                           \
        att[d] = sum16(p); }
      TLF_SCORE(0) TLF_SCORE(1) TLF_SCORE(2) TLF_SCORE(3)
#undef TLF_SCORE
      const float mx = fmaxf(fmaxf(att[0], att[1]), fmaxf(att[2], att[3]));
      const float e0 = __expf(att[0] - mx);
      const float e1 = __expf(att[1] - mx);
      const float e2 = __expf(att[2] - mx);
      const float e3 = __expf(att[3] - mx);
      const float inv = __builtin_amdgcn_rcpf(e0 + e1 + e2 + e3);
      wat[t][0] = e0 * inv; wat[t][1] = e1 * inv;
      wat[t][2] = e2 * inv; wat[t][3] = e3 * inv;
    }

    // ---- V + PV (ctx stays transposed/in-lane; pairwise tree) ----
    float ctx[2][4];
    #pragma unroll
    for (int t = 0; t < 2; ++t) {
      const f32x4 va = __builtin_amdgcn_mfma_f32_16x16x32_bf16(aw[4 + t], bx, ldc4(cg + 16 + 4 * t), 0, 0, 0);
      #pragma unroll
      for (int m = 0; m < 4; ++m) {
        float c01 = wat[t][0] * va[m];
        c01 = fmaf(wat[t][1], rot4<1>(va[m]), c01);
        float c23 = wat[t][2] * rot4<2>(va[m]);
        c23 = fmaf(wat[t][3], rot4<3>(va[m]), c23);
        ctx[t][m] = c01 + c23;
      }
    }

    // ---- out_proj + exact-f32 residual via C-in; LN1 ----
    const bf16x8 bc = pack8f(ctx[0][0], ctx[0][1], ctx[0][2], ctx[0][3],
                             ctx[1][0], ctx[1][1], ctx[1][2], ctx[1][3]);
    f32x4 y[2];
    #pragma unroll
    for (int t = 0; t < 2; ++t) {
      f32x4 sd = ldc4(cg + 24 + 4 * t);
      #pragma unroll
      for (int m = 0; m < 4; ++m) sd[m] += (t == 0) ? x0[m] : x1[m];
      y[t] = __builtin_amdgcn_mfma_f32_16x16x32_bf16(ao[t], bc, sd, 0, 0, 0);
    }
    float s = 0.f, ss = 0.f;
    #pragma unroll
    for (int t = 0; t < 2; ++t)
      #pragma unroll
      for (int m = 0; m < 4; ++m) { s += y[t][m]; ss = fmaf(y[t][m], y[t][m], ss); }
    s  = sum32(sum16(s));
    ss = sum32(sum16(ss));
    {
      const float mu  = s * 0.03125f;
      const float var = fmaf(ss, 0.03125f, -mu * mu);
      const float rs  = __builtin_amdgcn_rsqf(var + 1e-5f);
      #pragma unroll
      for (int t = 0; t < 2; ++t)
        #pragma unroll
        for (int m = 0; m < 4; ++m) y[t][m] = (y[t][m] - mu) * rs;  // ynorm
    }

    // ---- FFN1 (W1 pre-scaled by l1s; bias = b1') ----
    const bf16x8 bn = pack8f(y[0][0], y[0][1], y[0][2], y[0][3],
                             y[1][0], y[1][1], y[1][2], y[1][3]);
    f32x4 h[2];
    #pragma unroll
    for (int t = 0; t < 2; ++t) {
      h[t] = __builtin_amdgcn_mfma_f32_16x16x32_bf16(a1[t], bn, ldc4(cg + 32 + 4 * t), 0, 0, 0);
      #pragma unroll
      for (int m = 0; m < 4; ++m) h[t][m] = fmaxf(h[t][m], 0.f);
    }

    // ---- FFN2 + residual (ynorm*l1s + b2+l1b via C-in); LN2 ----
    const bf16x8 bh = pack8f(h[0][0], h[0][1], h[0][2], h[0][3],
                             h[1][0], h[1][1], h[1][2], h[1][3]);
    f32x4 d2[2];
    #pragma unroll
    for (int t = 0; t < 2; ++t) {
      const f32x4 l1s4 = ldc4(cg + 48 + 4 * t);
      const f32x4 b2q  = ldc4(cg + 40 + 4 * t);
      f32x4 sd;
      #pragma unroll
      for (int m = 0; m < 4; ++m) sd[m] = fmaf(y[t][m], l1s4[m], b2q[m]);
      d2[t] = __builtin_amdgcn_mfma_f32_16x16x32_bf16(a2[t], bh, sd, 0, 0, 0);
    }
    float s2 = 0.f, ss2 = 0.f;
    #pragma unroll
    for (int t = 0; t < 2; ++t)
      #pragma unroll
      for (int m = 0; m < 4; ++m) { s2 += d2[t][m]; ss2 = fmaf(d2[t][m], d2[t][m], ss2); }
    s2  = sum32(sum16(s2));
    ss2 = sum32(sum16(ss2));
    float x2[2][4];
    {
      const float mu  = s2 * 0.03125f;
      const float var = fmaf(ss2, 0.03125f, -mu * mu);
      const float rs  = __builtin_amdgcn_rsqf(var + 1e-5f);
      #pragma unroll
      for (int t = 0; t < 2; ++t) {
        const f32x4 l2s4 = ldc4(cg + 56 + 4 * t);
        const f32x4 l2b4 = ldc4(cg + 64 + 4 * t);
        #pragma unroll
        for (int m = 0; m < 4; ++m)
          x2[t][m] = fmaf((d2[t][m] - mu) * rs, l2s4[m], l2b4[m]);
      }
    }

    // ---- gated masked-softmax pooling (gate reduce + quad softmax) ----
    float gp = 0.f;
    #pragma unroll
    for (int t = 0; t < 2; ++t) {
      const f32x4 gw4 = ldc4(cg + 72 + 4 * t);
      #pragma unroll
      for (int m = 0; m < 4; ++m) gp = fmaf(x2[t][m], gw4[m], gp);
    }
    gp = sum32(sum16(gp));
    const float lg0 = (msk > 0.f) ? (gp + gbs) : -1e9f;
    const float lg1 = rot4<1>(lg0), lg2 = rot4<2>(lg0), lg3 = rot4<3>(lg0);
    const float mx  = fmaxf(fmaxf(lg0, lg1), fmaxf(lg2, lg3));
    const float e0 = __expf(lg0 - mx), e1 = __expf(lg1 - mx);
    const float e2 = __expf(lg2 - mx), e3 = __expf(lg3 - mx);
    const float m1 = rot4<1>(msk), m2 = rot4<2>(msk), m3 = rot4<3>(msk);
    const float em0 = e0 * msk, em1 = e1 * m1, em2 = e2 * m2, em3 = e3 * m3;
    const float se  = e0 + e1 + e2 + e3;
    const float invd = __builtin_amdgcn_rcpf((em0 + em1 + em2 + em3) + 1e-8f * se);
    const float wt0 = em0 * invd;  // own-token weight

    // fused[f] = quad-sum of wt_self * x2[f]
    float f8[2][4];
    #pragma unroll
    for (int t = 0; t < 2; ++t)
      #pragma unroll
      for (int m = 0; m < 4; ++m) {
        float v = x2[t][m] * wt0;
        v += dppf<0xB1>(v);
        v += dppf<0x4E>(v);
        f8[t][m] = v;
      }

    // ---- stores ----
    const int q = c >> 2, sl = c & 3;
    float* orow = out + (tile * 4 + q) * 32;
    if (sl == 0)
      *(float4*)(orow + g4) = make_float4(f8[0][0], f8[0][1], f8[0][2], f8[0][3]);
    if (sl == 1)
      *(float4*)(orow + 16 + g4) = make_float4(f8[1][0], f8[1][1], f8[1][2], f8[1][3]);
    if (sl == 2) {
      const float w0 = em0 * invd, w1_ = em1 * invd, w2_ = em2 * invd, w3_ = em3 * invd;
      // lane token = 2: tokens [0,1,2,3] are deltas [2,3,0,1]
      *(float4*)(out + (size_t)TLF_N * 32 + (tile * 4 + q) * 4) =
          make_float4(w2_, w3_, w0, w1_);
    }
  }
}

extern "C" void kernel_launch(void* const* d_in, const int* in_sizes, int n_in,
                              void* d_out, int out_size, void* d_ws, size_t ws_size,
                              hipStream_t stream) {
  tlf_kernel<<<TLF_GRID, 256, 0, stream>>>(
      (const float*)d_in[0],  (const float*)d_in[1],  (const float*)d_in[2],
      (const float*)d_in[3],  (const float*)d_in[4],  (const float*)d_in[5],
      (const float*)d_in[6],  (const float*)d_in[7],  (const float*)d_in[8],
      (const float*)d_in[9],  (const float*)d_in[10], (const float*)d_in[11],
      (const float*)d_in[12], (const float*)d_in[13], (const float*)d_in[14],
      (const float*)d_in[15], (const float*)d_in[16], (float*)d_out);
}

// Round 12
// 166.370 us; speedup vs baseline: 1.2627x; 1.2627x over previous
//
#include <hip/hip_runtime.h>

#define TLF_N     500000
#define TLF_ITERS 10
#define TLF_GRID  3125   // 3125 blocks * 10 iters * 4 waves * 4 data rows = 500000

typedef short bf16x8 __attribute__((ext_vector_type(8)));
typedef float f32x4  __attribute__((ext_vector_type(4)));
typedef int   i32x4  __attribute__((ext_vector_type(4)));

#define LDSFENCE asm volatile("s_waitcnt lgkmcnt(0)" ::: "memory")

__device__ __forceinline__ int cvt_pk(float lo, float hi) {
  int r;
  asm("v_cvt_pk_bf16_f32 %0, %1, %2" : "=v"(r) : "v"(lo), "v"(hi));
  return r;
}

__device__ __forceinline__ bf16x8 pack8f(float a0, float a1, float a2, float a3,
                                         float a4, float a5, float a6, float a7) {
  i32x4 r;
  r[0] = cvt_pk(a0, a1); r[1] = cvt_pk(a2, a3);
  r[2] = cvt_pk(a4, a5); r[3] = cvt_pk(a6, a7);
  return __builtin_bit_cast(bf16x8, r);
}

template<int CTRL>
__device__ __forceinline__ float dppf(float x) {
  return __builtin_bit_cast(float, __builtin_amdgcn_update_dpp(
      0, __builtin_bit_cast(int, x), CTRL, 0xF, 0xF, true));
}

// quad rotate by D: lane c receives value of lane (c&~3) | ((c+D)&3)
template<int D>
__device__ __forceinline__ float rot4(float x) {
  if constexpr (D == 0) return x;
  else if constexpr (D == 1) return dppf<0x39>(x);   // quad_perm [1,2,3,0]
  else if constexpr (D == 2) return dppf<0x4E>(x);   // quad_perm [2,3,0,1]
  else                       return dppf<0x93>(x);   // quad_perm [3,0,1,2]
}

__device__ __forceinline__ f32x4 ldc4(const float* p) {
  return *reinterpret_cast<const f32x4*>(p);
}

// NOTE (rounds 7-11): permlane16/32_swap reduces and the hb-folding + PV-tree
// restructure all regressed or broke correctness. Round 11's bundle spilled
// (~+19MB WRITE_SIZE) and cost 26%. This is the round-6 proven code, exactly.

__launch_bounds__(256, 4)
__global__ void tlf_kernel(const float* __restrict__ tokens,
                           const float* __restrict__ amask,
                           const float* __restrict__ type_emb,
                           const float* __restrict__ ipw,
                           const float* __restrict__ ipb,
                           const float* __restrict__ opw,
                           const float* __restrict__ opb,
                           const float* __restrict__ l1sv,
                           const float* __restrict__ l1bv,
                           const float* __restrict__ w1,
                           const float* __restrict__ b1v,
                           const float* __restrict__ w2,
                           const float* __restrict__ b2v,
                           const float* __restrict__ l2sv,
                           const float* __restrict__ l2bv,
                           const float* __restrict__ gwv,
                           const float* __restrict__ gbv,
                           float* __restrict__ out) {
  // wave-uniform per-g constants (f32, broadcast reads), shared by all 4 waves:
  // slots (4 floats each): 0..5 qkv bias | 6,7 bo | 8,9 b1' | 10,11 b2+l1b
  //                        | 12,13 l1s | 14,15 l2s | 16,17 l2b | 18,19 gw
  __shared__ float cLDS[4 * 80];

  const int w  = threadIdx.x >> 6;// wave 0..3
  const int l  = threadIdx.x & 63;
  const int g  = l >> 4;           // k-subgroup / channel block
  const int c  = l & 15;           // column lane: token-row within tile
  const int g4 = g << 2;

  const float isq = 0.3535533905932738f;  // 1/sqrt(HD)

  // ---- weight A-frags (rows 16t+c, k-cols P(8g+j) = {4g+j} U {16+4g+j}) ----
  bf16x8 aw[6], ao[2], a1[2], a2[2];
  #pragma unroll
  for (int t = 0; t < 6; ++t) {
    const float s = (t < 2) ? isq : 1.0f;
    const float* r0 = ipw + (16 * t + c) * 32;
    const float4 wa = *(const float4*)(r0 + g4);
    const float4 wb = *(const float4*)(r0 + 16 + g4);
    aw[t] = pack8f(wa.x * s, wa.y * s, wa.z * s, wa.w * s,
                   wb.x * s, wb.y * s, wb.z * s, wb.w * s);
  }
  const float4 ls0 = *(const float4*)(l1sv + g4);
  const float4 ls1 = *(const float4*)(l1sv + 16 + g4);
  #pragma unroll
  for (int t = 0; t < 2; ++t) {
    const float* r0 = opw + (16 * t + c) * 32;
    const float* r1 = w1  + (16 * t + c) * 32;
    const float* r2 = w2  + (16 * t + c) * 32;
    float4 wa, wb;
    wa = *(const float4*)(r0 + g4); wb = *(const float4*)(r0 + 16 + g4);
    ao[t] = pack8f(wa.x, wa.y, wa.z, wa.w, wb.x, wb.y, wb.z, wb.w);
    wa = *(const float4*)(r1 + g4); wb = *(const float4*)(r1 + 16 + g4);
    a1[t] = pack8f(wa.x * ls0.x, wa.y * ls0.y, wa.z * ls0.z, wa.w * ls0.w,
                   wb.x * ls1.x, wb.y * ls1.y, wb.z * ls1.z, wb.w * ls1.w);
    wa = *(const float4*)(r2 + g4); wb = *(const float4*)(r2 + 16 + g4);
    a2[t] = pack8f(wa.x, wa.y, wa.z, wa.w, wb.x, wb.y, wb.z, wb.w);
  }

  // ---- per-g constants -> LDS (all waves write identical values; in-wave
  //      write->read order via lgkmcnt; cross-wave writes are same-value) ----
  if (c == 0) {
    float* cp = cLDS + g * 80;
    #pragma unroll
    for (int t = 0; t < 6; ++t) {
      const float s = (t < 2) ? isq : 1.0f;
      #pragma unroll
      for (int m = 0; m < 4; ++m) cp[4 * t + m] = ipb[16 * t + g4 + m] * s;
    }
    #pragma unroll
    for (int t = 0; t < 2; ++t)
      #pragma unroll
      for (int m = 0; m < 4; ++m) {
        const int r = 16 * t + g4 + m;
        cp[24 + 4 * t + m] = opb[r];
        cp[40 + 4 * t + m] = b2v[r] + l1bv[r];
        cp[48 + 4 * t + m] = l1sv[r];
        cp[56 + 4 * t + m] = l2sv[r];
        cp[64 + 4 * t + m] = l2bv[r];
        cp[72 + 4 * t + m] = gwv[r];
      }
    // b1'[f2] = b1[f2] + sum_f l1b[f] * W1[f2][f]
    #pragma unroll
    for (int t = 0; t < 2; ++t)
      #pragma unroll
      for (int m = 0; m < 4; ++m) {
        const int r = 16 * t + g4 + m;
        float a = b1v[r];
        const float* wrow = w1 + r * 32;
        #pragma unroll
        for (int q8 = 0; q8 < 8; ++q8) {
          const float4 wv = *(const float4*)(wrow + q8 * 4);
          const float4 lb = *(const float4*)(l1bv + q8 * 4);
          a += wv.x * lb.x + wv.y * lb.y + wv.z * lb.z + wv.w * lb.w;
        }
        cp[32 + 4 * t + m] = a;
      }
  }
  LDSFENCE;

  // type_emb in B-frag layout: token m=c&3, channels P
  const float* tb = type_emb + (c & 3) * 32;
  const float4 te0 = *(const float4*)(tb + g4);
  const float4 te1 = *(const float4*)(tb + 16 + g4);
  const float gbs = gbv[0];

  // wave w handles tile = (block*ITERS + it)*4 + w  (block covers 64 contiguous
  // data rows per iteration -> coalesced across waves)
  const size_t tileW0 = ((size_t)blockIdx.x * TLF_ITERS) * 4 + w;

  // prologue prefetch
  float4 nxa, nxb; float nmsk;
  {
    const float* tp = tokens + (tileW0 * 16 + c) * 32;
    nxa = *(const float4*)(tp + g4);
    nxb = *(const float4*)(tp + 16 + g4);
    nmsk = amask[tileW0 * 16 + c];
  }

  for (int it = 0; it < TLF_ITERS; ++it) {
    const size_t tile = tileW0 + (size_t)it * 4;
    const float4 xa = nxa, xb = nxb;
    const float msk = nmsk;
    if (it + 1 < TLF_ITERS) {
      const float* tp = tokens + ((tile + 4) * 16 + c) * 32;
      nxa = *(const float4*)(tp + g4);
      nxb = *(const float4*)(tp + 16 + g4);
      nmsk = amask[(tile + 4) * 16 + c];
    }

    // LICM-defeating opaque offset for per-iter LDS const reads (32-bit, safe)
    int cgo = g * 80;
    asm volatile("" : "+v"(cgo));
    const float* cg = cLDS + cgo;

    // ---- x = tokens + te (f32, kept for exact residual) ----
    float x0[4] = {xa.x + te0.x, xa.y + te0.y, xa.z + te0.z, xa.w + te0.w};
    float x1[4] = {xb.x + te1.x, xb.y + te1.y, xb.z + te1.z, xb.w + te1.w};
    const bf16x8 bx = pack8f(x0[0], x0[1], x0[2], x0[3],
                             x1[0], x1[1], x1[2], x1[3]);

    // ---- Q, K (transposed outputs: lane(g,c) holds f=16t+4g+m, token c) ----
    f32x4 qa[2], ka[2];
    #pragma unroll
    for (int t = 0; t < 2; ++t)
      qa[t] = __builtin_amdgcn_mfma_f32_16x16x32_bf16(aw[t], bx, ldc4(cg + 4 * t), 0, 0, 0);
    #pragma unroll
    for (int t = 0; t < 2; ++t)
      ka[t] = __builtin_amdgcn_mfma_f32_16x16x32_bf16(aw[2 + t], bx, ldc4(cg + 8 + 4 * t), 0, 0, 0);

    // ---- scores + softmax (quad-DPP token rotations; xor16 joins head halves) ----
    const float bself = (msk > 0.f) ? 0.f : -1e9f;
    float wat[2][4];
    #pragma unroll
    for (int t = 0; t < 2; ++t) {
      float att[4];
#define TLF_SCORE(d)                                                        \
      { float p = qa[t][0] * rot4<d>(ka[t][0]);                             \
        p = fmaf(qa[t][1], rot4<d>(ka[t][1]), p);                           \
        p = fmaf(qa[t][2], rot4<d>(ka[t][2]), p);                           \
        p = fmaf(qa[t][3], rot4<d>(ka[t][3]), p);                           \
        p += __shfl_xor(p, 16, 64);                                         \
        att[d] = p + rot4<d>(bself); }
      TLF_SCORE(0) TLF_SCORE(1) TLF_SCORE(2) TLF_SCORE(3)
#undef TLF_SCORE
      const float mx = fmaxf(fmaxf(att[0], att[1]), fmaxf(att[2], att[3]));
      const float e0 = __expf(att[0] - mx);
      const float e1 = __expf(att[1] - mx);
      const float e2 = __expf(att[2] - mx);
      const float e3 = __expf(att[3] - mx);
      const float inv = __builtin_amdgcn_rcpf(e0 + e1 + e2 + e3);
      wat[t][0] = e0 * inv; wat[t][1] = e1 * inv;
      wat[t][2] = e2 * inv; wat[t][3] = e3 * inv;
    }

    // ---- V + PV (ctx stays transposed/in-lane) ----
    float ctx[2][4];
    #pragma unroll
    for (int t = 0; t < 2; ++t) {
      const f32x4 va = __builtin_amdgcn_mfma_f32_16x16x32_bf16(aw[4 + t], bx, ldc4(cg + 16 + 4 * t), 0, 0, 0);
#define TLF_PV(d)                                                           \
      { const float w_ = wat[t][d];                                         \
        ctx[t][0] = (d == 0) ? w_ * va[0] : fmaf(w_, rot4<d>(va[0]), ctx[t][0]); \
        ctx[t][1] = (d == 0) ? w_ * va[1] : fmaf(w_, rot4<d>(va[1]), ctx[t][1]); \
        ctx[t][2] = (d == 0) ? w_ * va[2] : fmaf(w_, rot4<d>(va[2]), ctx[t][2]); \
        ctx[t][3] = (d == 0) ? w_ * va[3] : fmaf(w_, rot4<d>(va[3]), ctx[t][3]); }
      TLF_PV(0) TLF_PV(1) TLF_PV(2) TLF_PV(3)
#undef TLF_PV
    }

    // ---- out_proj + exact-f32 residual via C-in; LN1 ----
    const bf16x8 bc = pack8f(ctx[0][0], ctx[0][1], ctx[0][2], ctx[0][3],
                             ctx[1][0], ctx[1][1], ctx[1][2], ctx[1][3]);
    f32x4 y[2];
    #pragma unroll
    for (int t = 0; t < 2; ++t) {
      f32x4 sd = ldc4(cg + 24 + 4 * t);
      #pragma unroll
      for (int m = 0; m < 4; ++m) sd[m] += (t == 0) ? x0[m] : x1[m];
      y[t] = __builtin_amdgcn_mfma_f32_16x16x32_bf16(ao[t], bc, sd, 0, 0, 0);
    }
    float s = 0.f, ss = 0.f;
    #pragma unroll
    for (int t = 0; t < 2; ++t)
      #pragma unroll
      for (int m = 0; m < 4; ++m) { s += y[t][m]; ss = fmaf(y[t][m], y[t][m], ss); }
    s  += __shfl_xor(s, 16, 64);  s  += __shfl_xor(s, 32, 64);
    ss += __shfl_xor(ss, 16, 64); ss += __shfl_xor(ss, 32, 64);
    {
      const float mu  = s * 0.03125f;
      const float var = fmaf(ss, 0.03125f, -mu * mu);
      const float rs  = __builtin_amdgcn_rsqf(var + 1e-5f);
      #pragma unroll
      for (int t = 0; t < 2; ++t)
        #pragma unroll
        for (int m = 0; m < 4; ++m) y[t][m] = (y[t][m] - mu) * rs;  // ynorm
    }

    // ---- FFN1 (W1 pre-scaled by l1s; bias = b1') ----
    const bf16x8 bn = pack8f(y[0][0], y[0][1], y[0][2], y[0][3],
                             y[1][0], y[1][1], y[1][2], y[1][3]);
    f32x4 h[2];
    #pragma unroll
    for (int t = 0; t < 2; ++t) {
      h[t] = __builtin_amdgcn_mfma_f32_16x16x32_bf16(a1[t], bn, ldc4(cg + 32 + 4 * t), 0, 0, 0);
      #pragma unroll
      for (int m = 0; m < 4; ++m) h[t][m] = fmaxf(h[t][m], 0.f);
    }

    // ---- FFN2 + residual (ynorm*l1s + b2+l1b via C-in); LN2 ----
    const bf16x8 bh = pack8f(h[0][0], h[0][1], h[0][2], h[0][3],
                             h[1][0], h[1][1], h[1][2], h[1][3]);
    f32x4 d2[2];
    #pragma unroll
    for (int t = 0; t < 2; ++t) {
      const f32x4 l1s4 = ldc4(cg + 48 + 4 * t);
      const f32x4 b2q  = ldc4(cg + 40 + 4 * t);
      f32x4 sd;
      #pragma unroll
      for (int m = 0; m < 4; ++m) sd[m] = fmaf(y[t][m], l1s4[m], b2q[m]);
      d2[t] = __builtin_amdgcn_mfma_f32_16x16x32_bf16(a2[t], bh, sd, 0, 0, 0);
    }
    float s2 = 0.f, ss2 = 0.f;
    #pragma unroll
    for (int t = 0; t < 2; ++t)
      #pragma unroll
      for (int m = 0; m < 4; ++m) { s2 += d2[t][m]; ss2 = fmaf(d2[t][m], d2[t][m], ss2); }
    s2  += __shfl_xor(s2, 16, 64);  s2  += __shfl_xor(s2, 32, 64);
    ss2 += __shfl_xor(ss2, 16, 64); ss2 += __shfl_xor(ss2, 32, 64);
    float x2[2][4];
    {
      const float mu  = s2 * 0.03125f;
      const float var = fmaf(ss2, 0.03125f, -mu * mu);
      const float rs  = __builtin_amdgcn_rsqf(var + 1e-5f);
      #pragma unroll
      for (int t = 0; t < 2; ++t) {
        const f32x4 l2s4 = ldc4(cg + 56 + 4 * t);
        const f32x4 l2b4 = ldc4(cg + 64 + 4 * t);
        #pragma unroll
        for (int m = 0; m < 4; ++m)
          x2[t][m] = fmaf((d2[t][m] - mu) * rs, l2s4[m], l2b4[m]);
      }
    }

    // ---- gated masked-softmax pooling (gate reduce + quad softmax) ----
    float gp = 0.f;
    #pragma unroll
    for (int t = 0; t < 2; ++t) {
      const f32x4 gw4 = ldc4(cg + 72 + 4 * t);
      #pragma unroll
      for (int m = 0; m < 4; ++m) gp = fmaf(x2[t][m], gw4[m], gp);
    }
    gp += __shfl_xor(gp, 16, 64); gp += __shfl_xor(gp, 32, 64);
    const float lg0 = (msk > 0.f) ? (gp + gbs) : -1e9f;
    const float lg1 = rot4<1>(lg0), lg2 = rot4<2>(lg0), lg3 = rot4<3>(lg0);
    const float mx  = fmaxf(fmaxf(lg0, lg1), fmaxf(lg2, lg3));
    const float e0 = __expf(lg0 - mx), e1 = __expf(lg1 - mx);
    const float e2 = __expf(lg2 - mx), e3 = __expf(lg3 - mx);
    const float m1 = rot4<1>(msk), m2 = rot4<2>(msk), m3 = rot4<3>(msk);
    const float em0 = e0 * msk, em1 = e1 * m1, em2 = e2 * m2, em3 = e3 * m3;
    const float se  = e0 + e1 + e2 + e3;
    const float invd = __builtin_amdgcn_rcpf((em0 + em1 + em2 + em3) + 1e-8f * se);
    const float wt0 = em0 * invd;  // own-token weight

    // fused[f] = quad-sum of wt_self * x2[f]
    float f8[2][4];
    #pragma unroll
    for (int t = 0; t < 2; ++t)
      #pragma unroll
      for (int m = 0; m < 4; ++m) {
        float v = x2[t][m] * wt0;
        v += dppf<0xB1>(v);
        v += dppf<0x4E>(v);
        f8[t][m] = v;
      }

    // ---- stores ----
    const int q = c >> 2, sl = c & 3;
    float* orow = out + (tile * 4 + q) * 32;
    if (sl == 0)
      *(float4*)(orow + g4) = make_float4(f8[0][0], f8[0][1], f8[0][2], f8[0][3]);
    if (sl == 1)
      *(float4*)(orow + 16 + g4) = make_float4(f8[1][0], f8[1][1], f8[1][2], f8[1][3]);
    if (sl == 2) {
      const float w0 = em0 * invd, w1_ = em1 * invd, w2_ = em2 * invd, w3_ = em3 * invd;
      // lane token = 2: tokens [0,1,2,3] are deltas [2,3,0,1]
      *(float4*)(out + (size_t)TLF_N * 32 + (tile * 4 + q) * 4) =
          make_float4(w2_, w3_, w0, w1_);
    }
  }
}

extern "C" void kernel_launch(void* const* d_in, const int* in_sizes, int n_in,
                              void* d_out, int out_size, void* d_ws, size_t ws_size,
                              hipStream_t stream) {
  tlf_kernel<<<TLF_GRID, 256, 0, stream>>>(
      (const float*)d_in[0],  (const float*)d_in[1],  (const float*)d_in[2],
      (const float*)d_in[3],  (const float*)d_in[4],  (const float*)d_in[5],
      (const float*)d_in[6],  (const float*)d_in[7],  (const float*)d_in[8],
      (const float*)d_in[9],  (const float*)d_in[10], (const float*)d_in[11],
      (const float*)d_in[12], (const float*)d_in[13], (const float*)d_in[14],
      (const float*)d_in[15], (const float*)d_in[16], (float*)d_out);
}